// Round 17
// baseline (36.164 us; speedup 1.0000x reference)
//
#include <hip/hip_runtime.h>
#include <hip/hip_bf16.h>

// Problem constants
#define Bn 32
#define Nn 2048
#define Mn 12
#define FIN 64
#define FOUT 25
#define HROW 32            // h row stride in floats: 128 B = exactly 1 cache line
#define EPSBN 1e-5f

#define K1_BLOCKS 1056     // (3 groups * 11 chunks) * 32 b   [b = blk & 31]
#define NPART K1_BLOCKS    // one BN partial row per block
#define K3_BLOCKS 2048     // 64 chunks(32 atoms) * 32 b  -> 8 blocks/CU
#define NROWS 65536        // B*N

// Measured budget (R13-R16): k1~6.5 k2~2 k3~6.7 k4~1 + 4x2.3 node ovh + ~6
// fixed = 31.6. k3's 6.7 vs ~2 model = ~39 LDS-pipe ops/thread (22 of them
// wT weight reads) serialized on the CU's single LDS unit — same disease
// R15 cured in k1 (-3.2us). This round: weights move to the VMEM/L1 path
// (2.8KB read-only table, L1-resident) via a k2-precomputed global wTg;
// k3's wT LDS tile + staging deleted. DS ops/thread 39 -> ~17.

// ---------------------------------------------------------------------------
// K1: grouped linear + relu -> h[B][N][HROW]; BN partials via LDS col sums.
// (R16 version, unchanged)
// ---------------------------------------------------------------------------
__global__ __launch_bounds__(256) void k1_typelinear(
    const float* __restrict__ atom,      // [B][N][FIN]
    const float* __restrict__ type_w,    // [3][FIN][FOUT]
    const float* __restrict__ type_b,    // [3][FOUT]
    float* __restrict__ h,               // [B][N][HROW]
    float* __restrict__ psum,            // [FOUT][NPART]
    float* __restrict__ psq)             // [FOUT][NPART]
{
    const int blk = blockIdx.x;
    const int b = blk & 31;
    const int t2 = blk >> 5;             // g*11 + chunk
    const int g = t2 / 11;
    const int chunk = t2 - g * 11;
    const int s0 = g * 683;
    const int e0 = (g == 2) ? 2048 : (g + 1) * 683;
    const int tid = threadIdx.x;
    const int a = tid & 63;              // atom row within chunk
    const int q = __builtin_amdgcn_readfirstlane(tid >> 6);  // SGPR wave id
    const int n0 = s0 + chunk * 64;

    __shared__ __align__(16) float at[64][65];   // atom tile -> result tile
    __shared__ float sm[3][64][26];              // partial-acc combine
    float (*sms)[9] = reinterpret_cast<float(*)[9]>(&sm[0][0][0]);  // [32][9]
    float (*sqs)[9] = reinterpret_cast<float(*)[9]>(&sm[1][0][0]);  // [32][9]

    // ---- Phase A: coalesced tile load (guarded against n >= Nn) ----
    {
        const float* gbase = atom + ((size_t)b * Nn + n0) * FIN;
        const int nrows = min(64, Nn - n0);
        #pragma unroll
        for (int i = 0; i < 4; ++i) {
            const int v = tid + 256 * i;         // 0..1023
            const int row = v >> 4, c16 = v & 15;
            if (row < nrows) {
                const float4 vv = *reinterpret_cast<const float4*>(
                    gbase + row * FIN + c16 * 4);
                *reinterpret_cast<float4*>(&at[row][4 * c16]) = vv;
            }
        }
    }
    __syncthreads();

    // ---- Phase B: K-split GEMM from LDS, s_load weights ----
    float acc[FOUT];
    #pragma unroll
    for (int o = 0; o < FOUT; ++o) acc[o] = 0.0f;
    {
        float av[16];
        #pragma unroll
        for (int i = 0; i < 4; ++i) {
            const float4 vv = *reinterpret_cast<const float4*>(
                &at[a][16 * q + 4 * i]);
            av[4 * i + 0] = vv.x; av[4 * i + 1] = vv.y;
            av[4 * i + 2] = vv.z; av[4 * i + 3] = vv.w;
        }
        const float* wg = type_w + (size_t)g * (FIN * FOUT) + q * 16 * FOUT;
        #pragma unroll
        for (int f = 0; f < 16; ++f) {
            const float x = av[f];
            #pragma unroll
            for (int o = 0; o < FOUT; ++o)
                acc[o] = fmaf(x, wg[f * FOUT + o], acc[o]);  // s_load weights
        }
    }

    // ---- Phase C: combine via sm; wave0 finalizes, stores h directly ----
    if (q > 0) {
        #pragma unroll
        for (int o = 0; o < FOUT; ++o) sm[q - 1][a][o] = acc[o];
    }
    __syncthreads();
    if (q == 0) {
        #pragma unroll
        for (int o = 0; o < FOUT; ++o)
            acc[o] += (sm[0][a][o] + sm[1][a][o]) + sm[2][a][o];
        const bool act = (n0 + a) < e0;
        if (act) {
            const float* bg = type_b + (size_t)g * FOUT;
            #pragma unroll
            for (int o = 0; o < FOUT; ++o)
                acc[o] = fmaxf(acc[o] + bg[o], 0.0f);
        } else {
            #pragma unroll
            for (int o = 0; o < FOUT; ++o) acc[o] = 0.0f;
        }
        if (act) {
            float* hp = h + ((size_t)b * Nn + n0 + a) * HROW;
            float4* hp4 = reinterpret_cast<float4*>(hp);
            #pragma unroll
            for (int i = 0; i < 6; ++i) {
                float4 v;
                v.x = acc[4 * i + 0]; v.y = acc[4 * i + 1];
                v.z = acc[4 * i + 2]; v.w = acc[4 * i + 3];
                hp4[i] = v;
            }
            {
                float4 v; v.x = acc[24]; v.y = 0.0f; v.z = 0.0f; v.w = 0.0f;
                hp4[6] = v;
            }
        }
        // writeback for D2 column sums (zeros for inactive rows)
        #pragma unroll
        for (int i = 0; i < 6; ++i) {
            float4 v;
            v.x = acc[4 * i + 0]; v.y = acc[4 * i + 1];
            v.z = acc[4 * i + 2]; v.w = acc[4 * i + 3];
            *reinterpret_cast<float4*>(&at[a][4 * i]) = v;
        }
        at[a][24] = acc[24];
    }
    __syncthreads();   // at[][] final; orders Phase-C sm reads before
                       // D2's sms/sqs overwrite (aliased space)

    // ---- Phase D2: BN partials via LDS column sums ----
    {
        const int o = tid >> 3;          // 0..31
        const int rg = tid & 7;          // 0..7
        if (o < FOUT) {
            float s = 0.0f, qq = 0.0f;
            #pragma unroll
            for (int r = 0; r < 8; ++r) {
                const float x = at[rg * 8 + r][o];
                s += x;
                qq = fmaf(x, x, qq);
            }
            sms[o][rg] = s;
            sqs[o][rg] = qq;
        }
    }
    __syncthreads();
    if (tid < FOUT) {
        float s = 0.0f, qq = 0.0f;
        #pragma unroll
        for (int r = 0; r < 8; ++r) {
            s  += sms[tid][r];
            qq += sqs[tid][r];
        }
        psum[(size_t)tid * NPART + blk] = s;
        psq [(size_t)tid * NPART + blk] = qq;
    }
}

// ---------------------------------------------------------------------------
// K2: reduce partials -> affine; ALSO precompute the transposed/folded conv
// weight table wTg[o][f]: f<25 -> conv_w[f][o]; 25 -> conv_b[o]; 26 ->
// out_w[o]; 27 -> 0.  Block c handles channel c's stats AND wTg row c.
// AC layout: A@[0..24] (pad 28), C@[28..52].
// ---------------------------------------------------------------------------
__global__ __launch_bounds__(256) void k2_bnstats(
    const float* __restrict__ psum,      // [FOUT][NPART]
    const float* __restrict__ psq,       // [FOUT][NPART]
    const float* __restrict__ gamma,
    const float* __restrict__ beta,
    const float* __restrict__ conv_w,    // [FOUT][FOUT]
    const float* __restrict__ conv_b,    // [FOUT]
    const float* __restrict__ out_w,     // [FOUT][1]
    float* __restrict__ AC,              // [64]
    float* __restrict__ wTg)             // [FOUT][28]
{
    const int c = blockIdx.x;            // channel 0..24
    const int tid = threadIdx.x;         // 256
    const int lane = tid & 63;
    const int w = tid >> 6;

    // wTg row c (28 floats by the first 28 threads; tiny strided reads)
    if (tid < 28) {
        float wv = 0.0f;
        if (tid < FOUT)      wv = conv_w[tid * FOUT + c];
        else if (tid == 25)  wv = conv_b[c];
        else if (tid == 26)  wv = out_w[c];
        wTg[c * 28 + tid] = wv;
    }

    const float4* ps4 = reinterpret_cast<const float4*>(psum + (size_t)c * NPART);
    const float4* pq4 = reinterpret_cast<const float4*>(psq  + (size_t)c * NPART);
    float4 v = ps4[tid];
    float4 qv = pq4[tid];
    float s1 = (v.x + v.y) + (v.z + v.w);
    float s2 = (qv.x + qv.y) + (qv.z + qv.w);
    if (tid < (NPART / 4 - 256)) {       // 264 total float4s
        float4 v2 = ps4[tid + 256];
        float4 q2 = pq4[tid + 256];
        s1 += (v2.x + v2.y) + (v2.z + v2.w);
        s2 += (q2.x + q2.y) + (q2.z + q2.w);
    }
    #pragma unroll
    for (int m = 1; m < 64; m <<= 1) {
        s1 += __shfl_xor(s1, m, 64);
        s2 += __shfl_xor(s2, m, 64);
    }
    __shared__ float r1[4], r2[4];
    if (lane == 0) { r1[w] = s1; r2[w] = s2; }
    __syncthreads();
    if (tid == 0) {
        const float S1 = (r1[0] + r1[1]) + (r1[2] + r1[3]);
        const float S2 = (r2[0] + r2[1]) + (r2[2] + r2[3]);
        const float inv_cnt = 1.0f / (float)NROWS;
        const float mean = S1 * inv_cnt;
        const float var = S2 * inv_cnt - mean * mean;
        const float aa = gamma[c] * rsqrtf(var + EPSBN);
        AC[c] = aa;
        AC[28 + c] = beta[c] - mean * aa;
    }
}

// ---------------------------------------------------------------------------
// K3: gather + BN + conv + relu + out_w dot.
// v17: conv weights read from GLOBAL wTg (L1-resident 2.8KB table, VMEM
// pipe) instead of an LDS tile — offloads ~22 of 39 DS-pipe ops/thread
// (the LDS unit serializes per-CU; R15 proved this effect in k1).
// ---------------------------------------------------------------------------
__global__ __launch_bounds__(256) void k3_conv(
    const float* __restrict__ h,         // [B][N][HROW]
    const float* __restrict__ bond,      // [B][N][M]
    const int*   __restrict__ adj,       // [B][N][M]
    const float* __restrict__ AC,        // [64]
    const float* __restrict__ wTg,       // [FOUT][28]
    float* __restrict__ pe)              // [K3_BLOCKS]
{
    const int blk = blockIdx.x;
    const int b = blk & 31;
    const int chunk = blk >> 5;          // 0..63, 32 atoms each
    const int tid = threadIdx.x;
    const int w = tid >> 6;
    const int lane = tid & 63;
    const int g3 = lane >> 3;            // atom within wave's 8
    const int c = lane & 7;              // 16B chunk / o-offset

    __shared__ __align__(16) float msgn_s[4][8][36];
    __shared__ float wsum[4];

    const float* hb = h + (size_t)b * (Nn * HROW);
    const int an = chunk * 32 + w * 8 + g3;
    const size_t arow = (size_t)b * Nn + an;

    const float4 Ai = *reinterpret_cast<const float4*>(AC + 4 * c);
    const float4 Ci = *reinterpret_cast<const float4*>(AC + 28 + 4 * c);

    const int4*   ajp = reinterpret_cast<const int4*>(adj + arow * Mn);
    const float4* bpp = reinterpret_cast<const float4*>(bond + arow * Mn);
    const int4 A0 = ajp[0], A1 = ajp[1], A2 = ajp[2];
    const float4 B0 = bpp[0], B1 = bpp[1], B2 = bpp[2];
    const int ai[12] = {A0.x, A0.y, A0.z, A0.w,
                        A1.x, A1.y, A1.z, A1.w,
                        A2.x, A2.y, A2.z, A2.w};
    const float bw[12] = {B0.x, B0.y, B0.z, B0.w,
                          B1.x, B1.y, B1.z, B1.w,
                          B2.x, B2.y, B2.z, B2.w};
    float4 macc = {0.0f, 0.0f, 0.0f, 0.0f};
    float bsum = 0.0f;
    #pragma unroll
    for (int j = 0; j < 12; ++j) {
        const float wj = bw[j];
        bsum += wj;
        const float4 hv = *reinterpret_cast<const float4*>(
            hb + (size_t)ai[j] * HROW + c * 4);
        macc.x = fmaf(wj, hv.x, macc.x);
        macc.y = fmaf(wj, hv.y, macc.y);
        macc.z = fmaf(wj, hv.z, macc.z);
        macc.w = fmaf(wj, hv.w, macc.w);
    }
    if (c < 7) {
        float4 mn;
        mn.x = fmaf(Ai.x, macc.x, Ci.x * bsum);
        mn.y = fmaf(Ai.y, macc.y, Ci.y * bsum);
        mn.z = fmaf(Ai.z, macc.z, Ci.z * bsum);
        mn.w = fmaf(Ai.w, macc.w, Ci.w * bsum);
        if (c == 6) { mn.y = 1.0f; mn.z = 0.0f; mn.w = 0.0f; }  // bias hook
        *reinterpret_cast<float4*>(&msgn_s[w][g3][4 * c]) = mn;
    }

    __syncthreads();                     // msgn tiles ready (cross-lane)

    const float* mrow = &msgn_s[w][g3][0];
    float msv[28];
    #pragma unroll
    for (int j = 0; j < 7; ++j) {
        const float4 mv = *reinterpret_cast<const float4*>(mrow + 4 * j);
        msv[4 * j + 0] = mv.x; msv[4 * j + 1] = mv.y;
        msv[4 * j + 2] = mv.z; msv[4 * j + 3] = mv.w;
    }
    float v = 0.0f;
    #pragma unroll
    for (int k = 0; k < 4; ++k) {
        const int o = c + 8 * k;
        if (o < FOUT) {
            const float4* wrow = reinterpret_cast<const float4*>(wTg + o * 28);
            float t = 0.0f, myow = 0.0f;
            #pragma unroll
            for (int j = 0; j < 7; ++j) {
                const float4 w4 = wrow[j];   // global, L1-hit broadcast
                t = fmaf(msv[4 * j + 0], w4.x, t);
                t = fmaf(msv[4 * j + 1], w4.y, t);
                t = fmaf(msv[4 * j + 2], w4.z, t);
                t = fmaf(msv[4 * j + 3], w4.w, t);
                if (j == 6) myow = w4.z;     // wTg[o][26] = out_w[o]
            }
            v += fmaxf(t, 0.0f) * myow;
        }
    }

    #pragma unroll
    for (int m = 1; m < 64; m <<= 1)
        v += __shfl_xor(v, m, 64);
    if (lane == 0) wsum[w] = v;
    __syncthreads();
    if (tid == 0) pe[blk] = (wsum[0] + wsum[1]) + (wsum[2] + wsum[3]);
}

// ---------------------------------------------------------------------------
// K4: final per-batch reduce + relu. 1 block x 256 threads over pe[2048].
// ---------------------------------------------------------------------------
__global__ __launch_bounds__(256) void k4_final(
    const float* __restrict__ pe,        // [K3_BLOCKS]
    const float* __restrict__ out_b,
    float* __restrict__ out)             // [B]
{
    const int tid = threadIdx.x;
    float s = 0.0f;
    #pragma unroll
    for (int j2 = 0; j2 < 8; ++j2) s += pe[tid + 256 * j2];
    __shared__ float sred[8][33];
    sred[tid >> 5][tid & 31] = s;
    __syncthreads();
    if (tid < Bn) {
        float t = 0.0f;
        #pragma unroll
        for (int cg = 0; cg < 8; ++cg) t += sred[cg][tid];
        out[tid] = fmaxf(t * (1.0f / (float)Nn) + out_b[0], 0.0f);
    }
}

// ---------------------------------------------------------------------------
extern "C" void kernel_launch(void* const* d_in, const int* in_sizes, int n_in,
                              void* d_out, int out_size, void* d_ws, size_t ws_size,
                              hipStream_t stream)
{
    const float* atom   = (const float*)d_in[0];
    const float* bond   = (const float*)d_in[1];
    const int*   adjm   = (const int*)  d_in[2];
    const float* type_w = (const float*)d_in[3];
    const float* type_b = (const float*)d_in[4];
    const float* gamma  = (const float*)d_in[5];
    const float* beta   = (const float*)d_in[6];
    const float* conv_w = (const float*)d_in[7];
    const float* conv_b = (const float*)d_in[8];
    const float* out_w  = (const float*)d_in[9];
    const float* out_b  = (const float*)d_in[10];
    float* out = (float*)d_out;

    float* ws = (float*)d_ws;
    float* h    = ws;                             // B*N*HROW = 2,097,152
    float* psum = h + (size_t)Bn * Nn * HROW;     // FOUT*NPART = 26,400
    float* psq  = psum + (size_t)FOUT * NPART;    // 26,400
    float* AC   = psq + (size_t)FOUT * NPART;     // 64
    float* pe   = AC + 64;                        // 2048
    float* wTg  = pe + K3_BLOCKS;                 // FOUT*28 = 700

    k1_typelinear<<<K1_BLOCKS, 256, 0, stream>>>(atom, type_w, type_b, h, psum, psq);
    k2_bnstats<<<FOUT, 256, 0, stream>>>(psum, psq, gamma, beta,
                                         conv_w, conv_b, out_w, AC, wTg);
    k3_conv<<<K3_BLOCKS, 256, 0, stream>>>(h, bond, adjm, AC, wTg, pe);
    k4_final<<<1, 256, 0, stream>>>(pe, out_b, out);
}

// Round 18
// 30.805 us; speedup vs baseline: 1.1740x; 1.1740x over previous
//
#include <hip/hip_runtime.h>
#include <hip/hip_bf16.h>

// Problem constants
#define Bn 32
#define Nn 2048
#define Mn 12
#define FIN 64
#define FOUT 25
#define HROW 32            // h row stride in floats: 128 B = exactly 1 cache line
#define EPSBN 1e-5f

#define K1_BLOCKS 1056     // (3 groups * 11 chunks) * 32 b   [b = blk & 31]
#define NPART K1_BLOCKS    // one BN partial row per block
#define K3_BLOCKS 2048     // 64 chunks(32 atoms) * 32 b  -> 8 blocks/CU
#define NROWS 65536        // B*N

// REVERT to R16 (best, 31.55us). R17's LDS->global weight move regressed
// +4.6us: per-lane-divergent o made each weight read fan to 8 lines via the
// TA at L1 latency; the LDS version is conflict-free broadcast (~5-12cyc).
// Measured budget: kernels ~16us (k1 6.5, k2 2, k3 6.7, k4 1; each ~floor),
// overhead ~15.5us (4 x 2.3 node + ~6 fixed) — structural: 4-stage dep
// chain, cross-block fusion primitives measured 8x worse on 8-XCD CDNA4.

// ---------------------------------------------------------------------------
// K1: grouped linear + relu -> h[B][N][HROW]; BN partials via LDS col sums.
// ---------------------------------------------------------------------------
__global__ __launch_bounds__(256) void k1_typelinear(
    const float* __restrict__ atom,      // [B][N][FIN]
    const float* __restrict__ type_w,    // [3][FIN][FOUT]
    const float* __restrict__ type_b,    // [3][FOUT]
    float* __restrict__ h,               // [B][N][HROW]
    float* __restrict__ psum,            // [FOUT][NPART]
    float* __restrict__ psq)             // [FOUT][NPART]
{
    const int blk = blockIdx.x;
    const int b = blk & 31;
    const int t2 = blk >> 5;             // g*11 + chunk
    const int g = t2 / 11;
    const int chunk = t2 - g * 11;
    const int s0 = g * 683;
    const int e0 = (g == 2) ? 2048 : (g + 1) * 683;
    const int tid = threadIdx.x;
    const int a = tid & 63;              // atom row within chunk
    const int q = __builtin_amdgcn_readfirstlane(tid >> 6);  // SGPR wave id
    const int n0 = s0 + chunk * 64;

    __shared__ __align__(16) float at[64][65];   // atom tile -> result tile
    __shared__ float sm[3][64][26];              // partial-acc combine
    float (*sms)[9] = reinterpret_cast<float(*)[9]>(&sm[0][0][0]);  // [32][9]
    float (*sqs)[9] = reinterpret_cast<float(*)[9]>(&sm[1][0][0]);  // [32][9]

    // ---- Phase A: coalesced tile load (guarded against n >= Nn) ----
    {
        const float* gbase = atom + ((size_t)b * Nn + n0) * FIN;
        const int nrows = min(64, Nn - n0);
        #pragma unroll
        for (int i = 0; i < 4; ++i) {
            const int v = tid + 256 * i;         // 0..1023
            const int row = v >> 4, c16 = v & 15;
            if (row < nrows) {
                const float4 vv = *reinterpret_cast<const float4*>(
                    gbase + row * FIN + c16 * 4);
                *reinterpret_cast<float4*>(&at[row][4 * c16]) = vv;
            }
        }
    }
    __syncthreads();

    // ---- Phase B: K-split GEMM from LDS, s_load weights ----
    float acc[FOUT];
    #pragma unroll
    for (int o = 0; o < FOUT; ++o) acc[o] = 0.0f;
    {
        float av[16];
        #pragma unroll
        for (int i = 0; i < 4; ++i) {
            const float4 vv = *reinterpret_cast<const float4*>(
                &at[a][16 * q + 4 * i]);
            av[4 * i + 0] = vv.x; av[4 * i + 1] = vv.y;
            av[4 * i + 2] = vv.z; av[4 * i + 3] = vv.w;
        }
        const float* wg = type_w + (size_t)g * (FIN * FOUT) + q * 16 * FOUT;
        #pragma unroll
        for (int f = 0; f < 16; ++f) {
            const float x = av[f];
            #pragma unroll
            for (int o = 0; o < FOUT; ++o)
                acc[o] = fmaf(x, wg[f * FOUT + o], acc[o]);  // s_load weights
        }
    }

    // ---- Phase C: combine via sm; wave0 finalizes, stores h directly ----
    if (q > 0) {
        #pragma unroll
        for (int o = 0; o < FOUT; ++o) sm[q - 1][a][o] = acc[o];
    }
    __syncthreads();
    if (q == 0) {
        #pragma unroll
        for (int o = 0; o < FOUT; ++o)
            acc[o] += (sm[0][a][o] + sm[1][a][o]) + sm[2][a][o];
        const bool act = (n0 + a) < e0;
        if (act) {
            const float* bg = type_b + (size_t)g * FOUT;
            #pragma unroll
            for (int o = 0; o < FOUT; ++o)
                acc[o] = fmaxf(acc[o] + bg[o], 0.0f);
        } else {
            #pragma unroll
            for (int o = 0; o < FOUT; ++o) acc[o] = 0.0f;
        }
        // direct h store (divergent per-lane rows — measured == coalesced)
        if (act) {
            float* hp = h + ((size_t)b * Nn + n0 + a) * HROW;
            float4* hp4 = reinterpret_cast<float4*>(hp);
            #pragma unroll
            for (int i = 0; i < 6; ++i) {
                float4 v;
                v.x = acc[4 * i + 0]; v.y = acc[4 * i + 1];
                v.z = acc[4 * i + 2]; v.w = acc[4 * i + 3];
                hp4[i] = v;
            }
            {
                float4 v; v.x = acc[24]; v.y = 0.0f; v.z = 0.0f; v.w = 0.0f;
                hp4[6] = v;
            }
        }
        // writeback for D2 column sums (zeros for inactive rows)
        #pragma unroll
        for (int i = 0; i < 6; ++i) {
            float4 v;
            v.x = acc[4 * i + 0]; v.y = acc[4 * i + 1];
            v.z = acc[4 * i + 2]; v.w = acc[4 * i + 3];
            *reinterpret_cast<float4*>(&at[a][4 * i]) = v;
        }
        at[a][24] = acc[24];
    }
    __syncthreads();   // at[][] final; orders Phase-C sm reads before
                       // D2's sms/sqs overwrite (aliased space)

    // ---- Phase D2: BN partials via LDS column sums (no butterflies) ----
    // thread (o = tid>>3, rg = tid&7) sums 8 rows of column o.
    // at stride 65: bank (row + o) % 32 -> exact 2-way alias (free, m136).
    {
        const int o = tid >> 3;          // 0..31
        const int rg = tid & 7;          // 0..7
        if (o < FOUT) {
            float s = 0.0f, qq = 0.0f;
            #pragma unroll
            for (int r = 0; r < 8; ++r) {
                const float x = at[rg * 8 + r][o];
                s += x;
                qq = fmaf(x, x, qq);
            }
            sms[o][rg] = s;
            sqs[o][rg] = qq;
        }
    }
    __syncthreads();
    if (tid < FOUT) {
        float s = 0.0f, qq = 0.0f;
        #pragma unroll
        for (int r = 0; r < 8; ++r) {
            s  += sms[tid][r];
            qq += sqs[tid][r];
        }
        psum[(size_t)tid * NPART + blk] = s;
        psq [(size_t)tid * NPART + blk] = qq;
    }
}

// ---------------------------------------------------------------------------
// K2: reduce partials -> affine. 25 blocks x 256 threads.
// AC layout: A@[0..24] (pad 28), C@[28..52].
// ---------------------------------------------------------------------------
__global__ __launch_bounds__(256) void k2_bnstats(
    const float* __restrict__ psum,      // [FOUT][NPART]
    const float* __restrict__ psq,       // [FOUT][NPART]
    const float* __restrict__ gamma,
    const float* __restrict__ beta,
    float* __restrict__ AC)              // [64]
{
    const int c = blockIdx.x;            // channel 0..24
    const int tid = threadIdx.x;         // 256
    const int lane = tid & 63;
    const int w = tid >> 6;
    const float4* ps4 = reinterpret_cast<const float4*>(psum + (size_t)c * NPART);
    const float4* pq4 = reinterpret_cast<const float4*>(psq  + (size_t)c * NPART);
    float4 v = ps4[tid];
    float4 qv = pq4[tid];
    float s1 = (v.x + v.y) + (v.z + v.w);
    float s2 = (qv.x + qv.y) + (qv.z + qv.w);
    if (tid < (NPART / 4 - 256)) {       // 264 total float4s
        float4 v2 = ps4[tid + 256];
        float4 q2 = pq4[tid + 256];
        s1 += (v2.x + v2.y) + (v2.z + v2.w);
        s2 += (q2.x + q2.y) + (q2.z + q2.w);
    }
    #pragma unroll
    for (int m = 1; m < 64; m <<= 1) {
        s1 += __shfl_xor(s1, m, 64);
        s2 += __shfl_xor(s2, m, 64);
    }
    __shared__ float r1[4], r2[4];
    if (lane == 0) { r1[w] = s1; r2[w] = s2; }
    __syncthreads();
    if (tid == 0) {
        const float S1 = (r1[0] + r1[1]) + (r1[2] + r1[3]);
        const float S2 = (r2[0] + r2[1]) + (r2[2] + r2[3]);
        const float inv_cnt = 1.0f / (float)NROWS;
        const float mean = S1 * inv_cnt;
        const float var = S2 * inv_cnt - mean * mean;
        const float aa = gamma[c] * rsqrtf(var + EPSBN);
        AC[c] = aa;
        AC[28 + c] = beta[c] - mean * aa;
    }
}

// ---------------------------------------------------------------------------
// K3: gather + BN + conv + relu + out_w dot. Weights in LDS wT (conflict-
// free broadcast reads: rows o=c+8k land on distinct bank-quads).
// ---------------------------------------------------------------------------
__global__ __launch_bounds__(256) void k3_conv(
    const float* __restrict__ h,         // [B][N][HROW]
    const float* __restrict__ bond,      // [B][N][M]
    const int*   __restrict__ adj,       // [B][N][M]
    const float* __restrict__ AC,        // [64]
    const float* __restrict__ conv_w,    // [FOUT][FOUT]
    const float* __restrict__ conv_b,    // [FOUT]
    const float* __restrict__ out_w,     // [FOUT][1]
    float* __restrict__ pe)              // [K3_BLOCKS]
{
    const int blk = blockIdx.x;
    const int b = blk & 31;
    const int chunk = blk >> 5;          // 0..63, 32 atoms each
    const int tid = threadIdx.x;
    const int w = tid >> 6;
    const int lane = tid & 63;
    const int g3 = lane >> 3;            // atom within wave's 8
    const int c = lane & 7;              // 16B chunk / o-offset

    __shared__ __align__(16) float wT[FOUT][28];
    __shared__ __align__(16) float msgn_s[4][8][36];
    __shared__ float wsum[4];

    for (int t = tid; t < FOUT * 28; t += 256) {
        const int o = t / 28, f = t - o * 28;
        float wv = 0.0f;
        if (f < FOUT)      wv = conv_w[f * FOUT + o];
        else if (f == 25)  wv = conv_b[o];
        else if (f == 26)  wv = out_w[o];
        wT[o][f] = wv;
    }

    const float* hb = h + (size_t)b * (Nn * HROW);
    const int an = chunk * 32 + w * 8 + g3;
    const size_t arow = (size_t)b * Nn + an;

    const float4 Ai = *reinterpret_cast<const float4*>(AC + 4 * c);
    const float4 Ci = *reinterpret_cast<const float4*>(AC + 28 + 4 * c);

    const int4*   ajp = reinterpret_cast<const int4*>(adj + arow * Mn);
    const float4* bpp = reinterpret_cast<const float4*>(bond + arow * Mn);
    const int4 A0 = ajp[0], A1 = ajp[1], A2 = ajp[2];
    const float4 B0 = bpp[0], B1 = bpp[1], B2 = bpp[2];
    const int ai[12] = {A0.x, A0.y, A0.z, A0.w,
                        A1.x, A1.y, A1.z, A1.w,
                        A2.x, A2.y, A2.z, A2.w};
    const float bw[12] = {B0.x, B0.y, B0.z, B0.w,
                          B1.x, B1.y, B1.z, B1.w,
                          B2.x, B2.y, B2.z, B2.w};
    float4 macc = {0.0f, 0.0f, 0.0f, 0.0f};
    float bsum = 0.0f;
    #pragma unroll
    for (int j = 0; j < 12; ++j) {
        const float wj = bw[j];
        bsum += wj;
        const float4 hv = *reinterpret_cast<const float4*>(
            hb + (size_t)ai[j] * HROW + c * 4);
        macc.x = fmaf(wj, hv.x, macc.x);
        macc.y = fmaf(wj, hv.y, macc.y);
        macc.z = fmaf(wj, hv.z, macc.z);
        macc.w = fmaf(wj, hv.w, macc.w);
    }
    if (c < 7) {
        float4 mn;
        mn.x = fmaf(Ai.x, macc.x, Ci.x * bsum);
        mn.y = fmaf(Ai.y, macc.y, Ci.y * bsum);
        mn.z = fmaf(Ai.z, macc.z, Ci.z * bsum);
        mn.w = fmaf(Ai.w, macc.w, Ci.w * bsum);
        if (c == 6) { mn.y = 1.0f; mn.z = 0.0f; mn.w = 0.0f; }  // bias hook
        *reinterpret_cast<float4*>(&msgn_s[w][g3][4 * c]) = mn;
    }

    __syncthreads();                     // wT + msgn tiles ready

    const float* mrow = &msgn_s[w][g3][0];
    float msv[28];
    #pragma unroll
    for (int j = 0; j < 7; ++j) {
        const float4 mv = *reinterpret_cast<const float4*>(mrow + 4 * j);
        msv[4 * j + 0] = mv.x; msv[4 * j + 1] = mv.y;
        msv[4 * j + 2] = mv.z; msv[4 * j + 3] = mv.w;
    }
    float v = 0.0f;
    #pragma unroll
    for (int k = 0; k < 4; ++k) {
        const int o = c + 8 * k;
        if (o < FOUT) {
            const float4* wrow = reinterpret_cast<const float4*>(&wT[o][0]);
            float t = 0.0f, myow = 0.0f;
            #pragma unroll
            for (int j = 0; j < 7; ++j) {
                const float4 w4 = wrow[j];
                t = fmaf(msv[4 * j + 0], w4.x, t);
                t = fmaf(msv[4 * j + 1], w4.y, t);
                t = fmaf(msv[4 * j + 2], w4.z, t);
                t = fmaf(msv[4 * j + 3], w4.w, t);
                if (j == 6) myow = w4.z;   // wT[o][26] = out_w[o]
            }
            v += fmaxf(t, 0.0f) * myow;
        }
    }

    #pragma unroll
    for (int m = 1; m < 64; m <<= 1)
        v += __shfl_xor(v, m, 64);
    if (lane == 0) wsum[w] = v;
    __syncthreads();
    if (tid == 0) pe[blk] = (wsum[0] + wsum[1]) + (wsum[2] + wsum[3]);
}

// ---------------------------------------------------------------------------
// K4: final per-batch reduce + relu. 1 block x 256 threads over pe[2048].
// ---------------------------------------------------------------------------
__global__ __launch_bounds__(256) void k4_final(
    const float* __restrict__ pe,        // [K3_BLOCKS]
    const float* __restrict__ out_b,
    float* __restrict__ out)             // [B]
{
    const int tid = threadIdx.x;
    float s = 0.0f;
    #pragma unroll
    for (int j2 = 0; j2 < 8; ++j2) s += pe[tid + 256 * j2];
    __shared__ float sred[8][33];
    sred[tid >> 5][tid & 31] = s;
    __syncthreads();
    if (tid < Bn) {
        float t = 0.0f;
        #pragma unroll
        for (int cg = 0; cg < 8; ++cg) t += sred[cg][tid];
        out[tid] = fmaxf(t * (1.0f / (float)Nn) + out_b[0], 0.0f);
    }
}

// ---------------------------------------------------------------------------
extern "C" void kernel_launch(void* const* d_in, const int* in_sizes, int n_in,
                              void* d_out, int out_size, void* d_ws, size_t ws_size,
                              hipStream_t stream)
{
    const float* atom   = (const float*)d_in[0];
    const float* bond   = (const float*)d_in[1];
    const int*   adjm   = (const int*)  d_in[2];
    const float* type_w = (const float*)d_in[3];
    const float* type_b = (const float*)d_in[4];
    const float* gamma  = (const float*)d_in[5];
    const float* beta   = (const float*)d_in[6];
    const float* conv_w = (const float*)d_in[7];
    const float* conv_b = (const float*)d_in[8];
    const float* out_w  = (const float*)d_in[9];
    const float* out_b  = (const float*)d_in[10];
    float* out = (float*)d_out;

    float* ws = (float*)d_ws;
    float* h    = ws;                             // B*N*HROW = 2,097,152
    float* psum = h + (size_t)Bn * Nn * HROW;     // FOUT*NPART = 26,400
    float* psq  = psum + (size_t)FOUT * NPART;    // 26,400
    float* AC   = psq + (size_t)FOUT * NPART;     // 64
    float* pe   = AC + 64;                        // 2048

    k1_typelinear<<<K1_BLOCKS, 256, 0, stream>>>(atom, type_w, type_b, h, psum, psq);
    k2_bnstats<<<FOUT, 256, 0, stream>>>(psum, psq, gamma, beta, AC);
    k3_conv<<<K3_BLOCKS, 256, 0, stream>>>(h, bond, adjm, AC, conv_w, conv_b, out_w, pe);
    k4_final<<<1, 256, 0, stream>>>(pe, out_b, out);
}